// Round 2
// baseline (1972.799 us; speedup 1.0000x reference)
//
#include <hip/hip_runtime.h>

#define HID 16
#define OUTC 4

// ---- degree: deg[dst] += 1 per edge (self-loop added in k_dinv) ----
__global__ void k_deg(const int* __restrict__ dst, float* __restrict__ deg, int E) {
    for (int i = blockIdx.x * blockDim.x + threadIdx.x; i < E; i += gridDim.x * blockDim.x)
        atomicAdd(deg + dst[i], 1.0f);
}

__global__ void k_dinv(float* __restrict__ deg, int N) {
    int i = blockIdx.x * blockDim.x + threadIdx.x;
    if (i < N) deg[i] = rsqrtf(deg[i] + 1.0f);   // +1 = self-loop; deg>0 always
}

// ---- m1[n][c] = x[n] * W1[c]  (IN_C == 1) ----
__global__ void k_m1(const float* __restrict__ x, const float* __restrict__ W1,
                     float* __restrict__ m, int N) {
    int t = blockIdx.x * blockDim.x + threadIdx.x;
    if (t < N * HID) {
        int n = t >> 4, c = t & 15;
        m[t] = x[n] * W1[c];
    }
}

// ---- edge scatter: agg[dst][c] += m[src][c] * dinv[src]*dinv[dst] ----
// thread t -> edge e = t/16, channel c = t%16
__global__ void k_edge(const int* __restrict__ src, const int* __restrict__ dst,
                       const float* __restrict__ dinv, const float* __restrict__ m,
                       float* __restrict__ agg, int E) {
    int total = E * HID;  // 204.8M < 2^31
    for (int t = blockIdx.x * blockDim.x + threadIdx.x; t < total; t += gridDim.x * blockDim.x) {
        int e = t >> 4, c = t & 15;
        int s = src[e], d = dst[e];
        float w = dinv[s] * dinv[d];
        atomicAdd(agg + d * HID + c, m[s * HID + c] * w);
    }
}

// ---- epilogue: h = relu(agg + selfloop + b), in place on agg ----
__global__ void k_post(const float* __restrict__ m, const float* __restrict__ dinv,
                       const float* __restrict__ b, float* __restrict__ agg, int N) {
    int t = blockIdx.x * blockDim.x + threadIdx.x;
    if (t < N * HID) {
        int n = t >> 4, c = t & 15;
        float dv = dinv[n];
        float v = agg[t] + m[t] * dv * dv + b[c];
        agg[t] = v > 0.f ? v : 0.f;
    }
}

// ---- m2[n][co] = sum_ci h[n][ci] * W2[ci][co] ----
__global__ void k_m2(const float* __restrict__ h, const float* __restrict__ W2,
                     float* __restrict__ m, int N) {
    __shared__ float w[HID * HID];
    if (threadIdx.x < HID * HID) w[threadIdx.x] = W2[threadIdx.x];
    __syncthreads();
    int t = blockIdx.x * blockDim.x + threadIdx.x;
    if (t < N * HID) {
        int n = t >> 4, co = t & 15;
        const float* hr = h + n * HID;
        float acc = 0.f;
#pragma unroll
        for (int ci = 0; ci < HID; ++ci) acc += hr[ci] * w[ci * HID + co];
        m[t] = acc;
    }
}

// ---- out[n][co] = sum_ci h2[n][ci] * Wl[ci][co] + bl[co] ----
__global__ void k_final(const float* __restrict__ h, const float* __restrict__ Wl,
                        const float* __restrict__ bl, float* __restrict__ out, int N) {
    __shared__ float w[HID * OUTC];
    if (threadIdx.x < HID * OUTC) w[threadIdx.x] = Wl[threadIdx.x];
    __syncthreads();
    int t = blockIdx.x * blockDim.x + threadIdx.x;
    if (t < N * OUTC) {
        int n = t >> 2, co = t & 3;
        const float* hr = h + n * HID;
        float acc = bl[co];
#pragma unroll
        for (int ci = 0; ci < HID; ++ci) acc += hr[ci] * w[ci * OUTC + co];
        out[t] = acc;
    }
}

extern "C" void kernel_launch(void* const* d_in, const int* in_sizes, int n_in,
                              void* d_out, int out_size, void* d_ws, size_t ws_size,
                              hipStream_t stream) {
    const float* x  = (const float*)d_in[0];
    const int* ed   = (const int*)d_in[1];     // harness delivers integer inputs as int32
    const float* W1 = (const float*)d_in[2];
    const float* b1 = (const float*)d_in[3];
    const float* W2 = (const float*)d_in[4];
    const float* b2 = (const float*)d_in[5];
    const float* Wl = (const float*)d_in[6];
    const float* bl = (const float*)d_in[7];
    float* out      = (float*)d_out;

    int N = in_sizes[0];      // IN_C == 1
    int E = in_sizes[1] / 2;
    const int* src = ed;
    const int* dst = ed + E;

    float* dinv = (float*)d_ws;            // N
    float* bufA = dinv + N;                // N*16  (transformed features m)
    float* bufB = bufA + (size_t)N * HID;  // N*16  (aggregation / hidden)

    int blk = 256;
    int gN16 = (N * HID + blk - 1) / blk;

    // degrees -> dinv
    hipMemsetAsync(dinv, 0, (size_t)N * sizeof(float), stream);
    k_deg<<<4096, blk, 0, stream>>>(dst, dinv, E);
    k_dinv<<<(N + blk - 1) / blk, blk, 0, stream>>>(dinv, N);

    // layer 1
    k_m1<<<gN16, blk, 0, stream>>>(x, W1, bufA, N);
    hipMemsetAsync(bufB, 0, (size_t)N * HID * sizeof(float), stream);
    k_edge<<<8192, blk, 0, stream>>>(src, dst, dinv, bufA, bufB, E);
    k_post<<<gN16, blk, 0, stream>>>(bufA, dinv, b1, bufB, N);   // bufB = h1

    // layer 2
    k_m2<<<gN16, blk, 0, stream>>>(bufB, W2, bufA, N);           // bufA = m2
    hipMemsetAsync(bufB, 0, (size_t)N * HID * sizeof(float), stream);
    k_edge<<<8192, blk, 0, stream>>>(src, dst, dinv, bufA, bufB, E);
    k_post<<<gN16, blk, 0, stream>>>(bufA, dinv, b2, bufB, N);   // bufB = h2

    // readout
    k_final<<<(N * OUTC + blk - 1) / blk, blk, 0, stream>>>(bufB, Wl, bl, out, N);
}